// Round 9
// baseline (167.403 us; speedup 1.0000x reference)
//
#include <hip/hip_runtime.h>

#define NB   32
#define NT   784
#define NC   768
#define NH   4
#define CH   192
#define PSZ  14
#define NP   196
#define RESO 28
#define EPSV 1e-5f
#define CSL  32            // channels per slice (inside one head: 192 = 6*32)
#define NSLC (NC / CSL)    // 24 slices
#define BTH  448           // 7 waves: thread = (jx = tid>>5, ch = tid&31)

// ---------------------------------------------------------------------------
// K1: wave-per-token group-m2 norm + per-token mean/var + 2x2 pool.
// grid = NB*NP blocks of 256 (4 waves = 4 tokens of one patch).
// Loads are FULLY COALESCED (lane-contiguous float4: row[lane], row[lane+64],
// row[lane+128] = 1 KB/wave-inst); per-head sums use masked accumulators +
// 6-round butterflies (R0-proven). VALU is idle here; TA/L1 path is not.
// ---------------------------------------------------------------------------
__global__ __launch_bounds__(256) void k_norm_pool(
    const float* __restrict__ x,
    float* __restrict__ inv_m2, float* __restrict__ mean_ln,
    float* __restrict__ var_ln, float4* __restrict__ xp4) {
  __shared__ float4 xl4[4 * 192];  // 12.3 KB
  int bid = blockIdx.x;
  int b = bid / NP, ip = bid % NP;
  int pr = ip / PSZ, pc = ip % PSZ;
  int tid = threadIdx.x;
  int k = tid >> 6, lane = tid & 63;
  int t = (2 * pr + (k >> 1)) * RESO + (2 * pc + (k & 1));

  const float4* row = (const float4*)(x + (size_t)(b * NT + t) * NC);
  float4 v0 = row[lane], v1 = row[lane + 64], v2 = row[lane + 128];
  // float4 p covers channels 4p..4p+3; head = p/48 (f4-aligned since 48|head)
  int h0 = lane / 48;            // 0 or 1
  int h1 = (lane + 64) / 48;     // 1 or 2
  int h2 = (lane + 128) / 48;    // 2 or 3

  float d0 = v0.x * v0.x + v0.y * v0.y + v0.z * v0.z + v0.w * v0.w;
  float d1 = v1.x * v1.x + v1.y * v1.y + v1.z * v1.z + v1.w * v1.w;
  float d2 = v2.x * v2.x + v2.y * v2.y + v2.z * v2.z + v2.w * v2.w;
  float s0 = (h0 == 0) ? d0 : 0.f;
  float s1 = ((h0 == 1) ? d0 : 0.f) + ((h1 == 1) ? d1 : 0.f);
  float s2 = ((h1 == 2) ? d1 : 0.f) + ((h2 == 2) ? d2 : 0.f);
  float s3 = (h2 == 3) ? d2 : 0.f;
#pragma unroll
  for (int d = 32; d >= 1; d >>= 1) {
    s0 += __shfl_xor(s0, d, 64);
    s1 += __shfl_xor(s1, d, 64);
    s2 += __shfl_xor(s2, d, 64);
    s3 += __shfl_xor(s3, d, 64);
  }
  float i0 = rsqrtf(s0 * (1.f / CH) + EPSV);
  float i1 = rsqrtf(s1 * (1.f / CH) + EPSV);
  float i2 = rsqrtf(s2 * (1.f / CH) + EPSV);
  float i3 = rsqrtf(s3 * (1.f / CH) + EPSV);
  if (lane < 4) {
    float iv = (lane == 0) ? i0 : (lane == 1) ? i1 : (lane == 2) ? i2 : i3;
    inv_m2[(size_t)(b * NT + t) * NH + lane] = iv;
  }

  float f0 = (h0 == 0) ? i0 : i1;
  float f1 = (h1 == 1) ? i1 : i2;
  float f2 = (h2 == 2) ? i2 : i3;
  v0.x *= f0; v0.y *= f0; v0.z *= f0; v0.w *= f0;
  v1.x *= f1; v1.y *= f1; v1.z *= f1; v1.w *= f1;
  v2.x *= f2; v2.y *= f2; v2.z *= f2; v2.w *= f2;

  float sm = v0.x + v0.y + v0.z + v0.w + v1.x + v1.y + v1.z + v1.w +
             v2.x + v2.y + v2.z + v2.w;
  float sq = v0.x * v0.x + v0.y * v0.y + v0.z * v0.z + v0.w * v0.w +
             v1.x * v1.x + v1.y * v1.y + v1.z * v1.z + v1.w * v1.w +
             v2.x * v2.x + v2.y * v2.y + v2.z * v2.z + v2.w * v2.w;
#pragma unroll
  for (int d = 32; d >= 1; d >>= 1) {
    sm += __shfl_xor(sm, d, 64);
    sq += __shfl_xor(sq, d, 64);
  }
  if (lane == 0) {
    float mean = sm / (float)NC;
    mean_ln[b * NT + t] = mean;
    var_ln[b * NT + t] = (sq - (float)NC * mean * mean) / (float)(NC - 1);
  }

  xl4[k * 192 + lane]       = v0;
  xl4[k * 192 + lane + 64]  = v1;
  xl4[k * 192 + lane + 128] = v2;
  __syncthreads();

  if (tid < 192) {
    float4 a = xl4[tid], bb = xl4[192 + tid], c = xl4[384 + tid], dd = xl4[576 + tid];
    float4 r;
    r.x = (a.x + bb.x + c.x + dd.x) * 0.25f;
    r.y = (a.y + bb.y + c.y + dd.y) * 0.25f;
    r.z = (a.z + bb.z + c.z + dd.z) * 0.25f;
    r.w = (a.w + bb.w + c.w + dd.w) * 0.25f;
    xp4[(size_t)(b * NP + ip) * 192 + tid] = r;
  }
}

// ---------------------------------------------------------------------------
// K2: separable conv + blend + affine + store; LDS-staged xp slice and
// vectorized epilogue via in-LDS mb/vb transpose. UNCHANGED from R8.
// grid = NB*NSLC = 768 blocks of 448 (XCD-swizzled; 3/CU resident).
// ---------------------------------------------------------------------------
__global__ __launch_bounds__(BTH) void k_fused(
    const float4* __restrict__ xp4, const float* __restrict__ pos_w,
    const float* __restrict__ mnw, const float* __restrict__ vnw,
    const float4* __restrict__ x4,
    const float4* __restrict__ weight4, const float4* __restrict__ bias4,
    const float* __restrict__ inv_m2, const float* __restrict__ mean_ln,
    const float* __restrict__ var_ln, float4* __restrict__ out4) {
  __shared__ float4 sxp4[NP * (CSL / 4)];  // 25088 B; REUSED as smv after Pass A
  __shared__ float sF[PSZ * PSZ];          // F table for head hs (jx rows)
  __shared__ float sG[PSZ * PSZ];          // G table for head hs (jy rows)
  __shared__ float tstat[NT][3];           // per token: inv_m2[hs], mean, var
  __shared__ float4 sWB[2][CSL / 4];       // weight4 / bias4 for this slice

  int bid0 = blockIdx.x;
  int bidS = (bid0 & 7) * 96 + (bid0 >> 3);  // bijective XCD swizzle (768 = 8*96)
  int b = bidS / NSLC, s = bidS % NSLC;
  int hs = s / 6;                            // head of this 32-channel slice
  int tid = threadIdx.x;
  int jx = tid >> 5;                         // 0..13 (half-wave uniform)
  int ch = tid & 31;

  // ---- per-head separable softmax tables (disjoint thread ranges)
  if (tid < PSZ) {                       // F row jf = tid: w0 on x-axis
    int jf = tid;
    float w0 = pos_w[hs * 3 + 0], w2 = pos_w[hs * 3 + 2];
    float e[PSZ], mx = -1e30f;
#pragma unroll
    for (int i = 0; i < PSZ; ++i) {
      float dd = (float)(jf - i);
      float sc = w0 * dd + w2 * dd * dd;
      e[i] = sc; mx = fmaxf(mx, sc);
    }
    float sum = 0.f;
#pragma unroll
    for (int i = 0; i < PSZ; ++i) { e[i] = expf(e[i] - mx); sum += e[i]; }
    float invs = 1.f / sum;
#pragma unroll
    for (int i = 0; i < PSZ; ++i) sF[jf * PSZ + i] = e[i] * invs;
  }
  if (tid >= 64 && tid < 64 + PSZ) {     // G row jr = tid-64: w1 on y-axis
    int jr = tid - 64;
    float w1 = pos_w[hs * 3 + 1], w2 = pos_w[hs * 3 + 2];
    float e[PSZ], mx = -1e30f;
#pragma unroll
    for (int i = 0; i < PSZ; ++i) {
      float dd = (float)(jr - i);
      float sc = w1 * dd + w2 * dd * dd;
      e[i] = sc; mx = fmaxf(mx, sc);
    }
    float sum = 0.f;
#pragma unroll
    for (int i = 0; i < PSZ; ++i) { e[i] = expf(e[i] - mx); sum += e[i]; }
    float invs = 1.f / sum;
#pragma unroll
    for (int i = 0; i < PSZ; ++i) sG[jr * PSZ + i] = e[i] * invs;
  }
  if (tid >= 128 && tid < 128 + CSL / 4) {          // weight slice
    sWB[0][tid - 128] = weight4[s * (CSL / 4) + (tid - 128)];
  }
  if (tid >= 160 && tid < 160 + CSL / 4) {          // bias slice
    sWB[1][tid - 160] = bias4[s * (CSL / 4) + (tid - 160)];
  }

  // ---- stage xp slice: 1568 float4, coalesced 128B runs per patch
  {
    const float4* src = xp4 + (size_t)b * NP * (NC / 4) + s * (CSL / 4);
    for (int i = tid; i < NP * (CSL / 4); i += BTH) {
      int p = i >> 3, q = i & 7;
      sxp4[i] = src[(size_t)p * (NC / 4) + q];
    }
  }
  // ---- stage per-token stats for head hs
  for (int i = tid; i < NT; i += BTH) {
    size_t o = (size_t)(b * NT + i);
    tstat[i][0] = inv_m2[o * NH + hs];
    tstat[i][1] = mean_ln[o];
    tstat[i][2] = var_ln[o];
  }

  // gates: uniform per block, compute per-thread (hides under staging)
  float mw = 1.f / (1.f + expf(-mnw[hs]));
  float vw = 1.f / (1.f + expf(-vnw[hs]));
  float omw = 1.f - mw, ovw = 1.f - vw;

  __syncthreads();

  // ---- Pass A: x-direction 14-tap contraction from LDS (bank = ch: clean)
  float t1[PSZ], t2[PSZ];
#pragma unroll
  for (int iy = 0; iy < PSZ; ++iy) { t1[iy] = 0.f; t2[iy] = 0.f; }

  const float* sx = (const float*)sxp4;
#pragma unroll
  for (int iy = 0; iy < PSZ; ++iy) {
#pragma unroll
    for (int ix = 0; ix < PSZ; ++ix) {
      float f = sF[jx * PSZ + ix];              // half-wave uniform broadcast
      float v = sx[(iy * PSZ + ix) * CSL + ch]; // conflict-free
      t1[iy] += f * v;
      t2[iy] += f * (v * v);
    }
  }
  __syncthreads();   // all Pass-A reads done -> sxp4 space reusable as smv

  // ---- Pass B + vectorized epilogue, chunked per 2 jy.
  // smv layout (floats, inside sxp4): [m/v 0..1 via +2][jyl 0..1][jx 0..13][ch 0..31]
  float* smv = (float*)sxp4;   // uses 2*2*14*32*4 = 7168 B of 25088
  const float4* xb = x4 + (size_t)b * NT * (NC / 4) + s * (CSL / 4);
  float4* ob = out4 + (size_t)b * NT * (NC / 4) + s * (CSL / 4);

#pragma unroll 1
  for (int chunk = 0; chunk < 7; ++chunk) {
    // Pass B for jy = 2*chunk + {0,1}
#pragma unroll
    for (int jyl = 0; jyl < 2; ++jyl) {
      int jy = chunk * 2 + jyl;
      float m = 0.f, q = 0.f;
#pragma unroll
      for (int iy = 0; iy < PSZ; ++iy) {
        float g = sG[jy * PSZ + iy];  // half-wave uniform broadcast
        m += g * t1[iy];
        q += g * t2[iy];
      }
      float p = fmaxf(q - m * m, 0.f);
      smv[(jyl * PSZ + jx) * CSL + ch]            = omw * m;  // mb
      smv[((2 + jyl) * PSZ + jx) * CSL + ch]      = ovw * p;  // vb
    }
    __syncthreads();

    // epilogue for token rows 4*chunk .. 4*chunk+3 (896 f4-items, 2/thread)
#pragma unroll
    for (int k = 0; k < 2; ++k) {
      int w = tid + BTH * k;          // 0..895
      int slot = w & 7;               // f4 slot within slice
      int r2 = w >> 3;                // 0..111
      int tcol = r2 % 28, trl = r2 / 28;
      int trow = chunk * 4 + trl;
      int t = trow * RESO + tcol;
      int jyl = trl >> 1, jx2 = tcol >> 1;

      float4 mb4 = *(const float4*)&smv[(jyl * PSZ + jx2) * CSL + slot * 4];
      float4 vb4 = *(const float4*)&smv[((2 + jyl) * PSZ + jx2) * CSL + slot * 4];
      float ivv = tstat[t][0];
      float mr = mw * tstat[t][1];
      float vr = vw * tstat[t][2] + EPSV;
      float4 wv = sWB[0][slot], bv = sWB[1][slot];

      float4 xv = xb[(size_t)t * (NC / 4) + slot];
      float4 r;
      r.x = (xv.x * ivv - (mb4.x + mr)) * rsqrtf(vb4.x + vr) * wv.x + bv.x;
      r.y = (xv.y * ivv - (mb4.y + mr)) * rsqrtf(vb4.y + vr) * wv.y + bv.y;
      r.z = (xv.z * ivv - (mb4.z + mr)) * rsqrtf(vb4.z + vr) * wv.z + bv.z;
      r.w = (xv.w * ivv - (mb4.w + mr)) * rsqrtf(vb4.w + vr) * wv.w + bv.w;
      ob[(size_t)t * (NC / 4) + slot] = r;
    }
    __syncthreads();   // before next chunk overwrites smv
  }
}

// ---------------------------------------------------------------------------
extern "C" void kernel_launch(void* const* d_in, const int* in_sizes, int n_in,
                              void* d_out, int out_size, void* d_ws, size_t ws_size,
                              hipStream_t stream) {
  const float* x     = (const float*)d_in[0];
  const float* wgt   = (const float*)d_in[1];
  const float* bias  = (const float*)d_in[2];
  const float* mnw   = (const float*)d_in[3];
  const float* vnw   = (const float*)d_in[4];
  const float* pos_w = (const float*)d_in[5];
  // pos_b (d_in[6]) cancels in the softmax — unused.
  float* out = (float*)d_out;

  float* ws      = (float*)d_ws;
  float* inv_m2  = ws;                              // NB*NT*NH = 100352
  float* mean_ln = inv_m2 + (size_t)NB * NT * NH;   // 25088
  float* var_ln  = mean_ln + (size_t)NB * NT;       // 25088
  float* xp      = var_ln + (size_t)NB * NT;        // NB*NP*NC = 4816896 (16B aligned)
  // total ~19.9 MB of workspace

  hipLaunchKernelGGL(k_norm_pool, dim3(NB * NP), dim3(256), 0, stream,
                     x, inv_m2, mean_ln, var_ln, (float4*)xp);
  hipLaunchKernelGGL(k_fused, dim3(NB * NSLC), dim3(BTH), 0, stream,
                     (const float4*)xp, pos_w, mnw, vnw, (const float4*)x,
                     (const float4*)wgt, (const float4*)bias,
                     inv_m2, mean_ln, var_ln, (float4*)out);
}

// Round 10
// 166.825 us; speedup vs baseline: 1.0035x; 1.0035x over previous
//
#include <hip/hip_runtime.h>

#define NB   32
#define NT   784
#define NC   768
#define NH   4
#define CH   192
#define PSZ  14
#define NP   196
#define RESO 28
#define EPSV 1e-5f
#define CSL  32            // channels per slice (inside one head: 192 = 6*32)
#define NSLC (NC / CSL)    // 24 slices
#define BTH  448           // 7 waves: thread = (jx = tid>>5, ch = tid&31)

// ---------------------------------------------------------------------------
// K1: wave-per-token group-m2 norm + per-token mean/var + 2x2 pool.
// grid = NB*NP blocks of 256 (4 waves = 4 tokens of one patch).
// Head-aligned lanes (R8-measured best: 165.1 vs 167.4 for coalesced-load
// variant): lane L owns head L/16, channels (L%16)*12..+11 -> m2 reduce is
// 4 shfl rounds in a 16-lane group; strided loads cost nothing measurable.
// ---------------------------------------------------------------------------
__global__ __launch_bounds__(256) void k_norm_pool(
    const float* __restrict__ x,
    float* __restrict__ inv_m2, float* __restrict__ mean_ln,
    float* __restrict__ var_ln, float4* __restrict__ xp4) {
  __shared__ float4 xl4[4 * 192];  // 12.3 KB
  int bid = blockIdx.x;
  int b = bid / NP, ip = bid % NP;
  int pr = ip / PSZ, pc = ip % PSZ;
  int tid = threadIdx.x;
  int k = tid >> 6, lane = tid & 63;
  int t = (2 * pr + (k >> 1)) * RESO + (2 * pc + (k & 1));

  const float4* row = (const float4*)(x + (size_t)(b * NT + t) * NC);
  int f4b = (lane >> 4) * 48 + (lane & 15) * 3;  // lane's base float4 index
  float4 v0 = row[f4b], v1 = row[f4b + 1], v2 = row[f4b + 2];

  // group-m2: all 12 channels of this lane belong to one head
  float d = v0.x * v0.x + v0.y * v0.y + v0.z * v0.z + v0.w * v0.w +
            v1.x * v1.x + v1.y * v1.y + v1.z * v1.z + v1.w * v1.w +
            v2.x * v2.x + v2.y * v2.y + v2.z * v2.z + v2.w * v2.w;
#pragma unroll
  for (int s = 1; s <= 8; s <<= 1) d += __shfl_xor(d, s, 64);
  float iv = rsqrtf(d * (1.f / CH) + EPSV);
  if ((lane & 15) == 0)
    inv_m2[(size_t)(b * NT + t) * NH + (lane >> 4)] = iv;

  v0.x *= iv; v0.y *= iv; v0.z *= iv; v0.w *= iv;
  v1.x *= iv; v1.y *= iv; v1.z *= iv; v1.w *= iv;
  v2.x *= iv; v2.y *= iv; v2.z *= iv; v2.w *= iv;

  float sm = v0.x + v0.y + v0.z + v0.w + v1.x + v1.y + v1.z + v1.w +
             v2.x + v2.y + v2.z + v2.w;
  float sq = v0.x * v0.x + v0.y * v0.y + v0.z * v0.z + v0.w * v0.w +
             v1.x * v1.x + v1.y * v1.y + v1.z * v1.z + v1.w * v1.w +
             v2.x * v2.x + v2.y * v2.y + v2.z * v2.z + v2.w * v2.w;
#pragma unroll
  for (int s = 1; s <= 32; s <<= 1) {
    sm += __shfl_xor(sm, s, 64);
    sq += __shfl_xor(sq, s, 64);
  }
  if (lane == 0) {
    float mean = sm / (float)NC;
    mean_ln[b * NT + t] = mean;
    var_ln[b * NT + t] = (sq - (float)NC * mean * mean) / (float)(NC - 1);
  }

  xl4[k * 192 + f4b]     = v0;
  xl4[k * 192 + f4b + 1] = v1;
  xl4[k * 192 + f4b + 2] = v2;
  __syncthreads();

  if (tid < 192) {
    float4 a = xl4[tid], bb = xl4[192 + tid], c = xl4[384 + tid], dd = xl4[576 + tid];
    float4 r;
    r.x = (a.x + bb.x + c.x + dd.x) * 0.25f;
    r.y = (a.y + bb.y + c.y + dd.y) * 0.25f;
    r.z = (a.z + bb.z + c.z + dd.z) * 0.25f;
    r.w = (a.w + bb.w + c.w + dd.w) * 0.25f;
    xp4[(size_t)(b * NP + ip) * 192 + tid] = r;
  }
}

// ---------------------------------------------------------------------------
// K2: separable conv + blend + affine + store; LDS-staged xp slice and
// vectorized epilogue via in-LDS mb/vb transpose, now DOUBLE-BUFFERED:
// Pass B for chunk k+1 writes smv[(k+1)&1] while epilogue k reads smv[k&1]
// -> 1 barrier per chunk instead of 2.
// grid = NB*NSLC = 768 blocks of 448 (XCD-swizzled; 3/CU resident).
// ---------------------------------------------------------------------------
__global__ __launch_bounds__(BTH) void k_fused(
    const float4* __restrict__ xp4, const float* __restrict__ pos_w,
    const float* __restrict__ mnw, const float* __restrict__ vnw,
    const float4* __restrict__ x4,
    const float4* __restrict__ weight4, const float4* __restrict__ bias4,
    const float* __restrict__ inv_m2, const float* __restrict__ mean_ln,
    const float* __restrict__ var_ln, float4* __restrict__ out4) {
  __shared__ float4 sxp4[NP * (CSL / 4)];  // 25088 B; REUSED as smv[2] after Pass A
  __shared__ float sF[PSZ * PSZ];          // F table for head hs (jx rows)
  __shared__ float sG[PSZ * PSZ];          // G table for head hs (jy rows)
  __shared__ float tstat[NT][3];           // per token: inv_m2[hs], mean, var
  __shared__ float4 sWB[2][CSL / 4];       // weight4 / bias4 for this slice

  int bid0 = blockIdx.x;
  int bidS = (bid0 & 7) * 96 + (bid0 >> 3);  // bijective XCD swizzle (768 = 8*96)
  int b = bidS / NSLC, s = bidS % NSLC;
  int hs = s / 6;                            // head of this 32-channel slice
  int tid = threadIdx.x;
  int jx = tid >> 5;                         // 0..13 (half-wave uniform)
  int ch = tid & 31;

  // ---- per-head separable softmax tables (disjoint thread ranges)
  if (tid < PSZ) {                       // F row jf = tid: w0 on x-axis
    int jf = tid;
    float w0 = pos_w[hs * 3 + 0], w2 = pos_w[hs * 3 + 2];
    float e[PSZ], mx = -1e30f;
#pragma unroll
    for (int i = 0; i < PSZ; ++i) {
      float dd = (float)(jf - i);
      float sc = w0 * dd + w2 * dd * dd;
      e[i] = sc; mx = fmaxf(mx, sc);
    }
    float sum = 0.f;
#pragma unroll
    for (int i = 0; i < PSZ; ++i) { e[i] = expf(e[i] - mx); sum += e[i]; }
    float invs = 1.f / sum;
#pragma unroll
    for (int i = 0; i < PSZ; ++i) sF[jf * PSZ + i] = e[i] * invs;
  }
  if (tid >= 64 && tid < 64 + PSZ) {     // G row jr = tid-64: w1 on y-axis
    int jr = tid - 64;
    float w1 = pos_w[hs * 3 + 1], w2 = pos_w[hs * 3 + 2];
    float e[PSZ], mx = -1e30f;
#pragma unroll
    for (int i = 0; i < PSZ; ++i) {
      float dd = (float)(jr - i);
      float sc = w1 * dd + w2 * dd * dd;
      e[i] = sc; mx = fmaxf(mx, sc);
    }
    float sum = 0.f;
#pragma unroll
    for (int i = 0; i < PSZ; ++i) { e[i] = expf(e[i] - mx); sum += e[i]; }
    float invs = 1.f / sum;
#pragma unroll
    for (int i = 0; i < PSZ; ++i) sG[jr * PSZ + i] = e[i] * invs;
  }
  if (tid >= 128 && tid < 128 + CSL / 4) {          // weight slice
    sWB[0][tid - 128] = weight4[s * (CSL / 4) + (tid - 128)];
  }
  if (tid >= 160 && tid < 160 + CSL / 4) {          // bias slice
    sWB[1][tid - 160] = bias4[s * (CSL / 4) + (tid - 160)];
  }

  // ---- stage xp slice: 1568 float4, coalesced 128B runs per patch
  {
    const float4* src = xp4 + (size_t)b * NP * (NC / 4) + s * (CSL / 4);
    for (int i = tid; i < NP * (CSL / 4); i += BTH) {
      int p = i >> 3, q = i & 7;
      sxp4[i] = src[(size_t)p * (NC / 4) + q];
    }
  }
  // ---- stage per-token stats for head hs
  for (int i = tid; i < NT; i += BTH) {
    size_t o = (size_t)(b * NT + i);
    tstat[i][0] = inv_m2[o * NH + hs];
    tstat[i][1] = mean_ln[o];
    tstat[i][2] = var_ln[o];
  }

  // gates: uniform per block, compute per-thread (hides under staging)
  float mw = 1.f / (1.f + expf(-mnw[hs]));
  float vw = 1.f / (1.f + expf(-vnw[hs]));
  float omw = 1.f - mw, ovw = 1.f - vw;

  __syncthreads();

  // ---- Pass A: x-direction 14-tap contraction from LDS (bank = ch: clean)
  float t1[PSZ], t2[PSZ];
#pragma unroll
  for (int iy = 0; iy < PSZ; ++iy) { t1[iy] = 0.f; t2[iy] = 0.f; }

  const float* sx = (const float*)sxp4;
#pragma unroll
  for (int iy = 0; iy < PSZ; ++iy) {
#pragma unroll
    for (int ix = 0; ix < PSZ; ++ix) {
      float f = sF[jx * PSZ + ix];              // half-wave uniform broadcast
      float v = sx[(iy * PSZ + ix) * CSL + ch]; // conflict-free
      t1[iy] += f * v;
      t2[iy] += f * (v * v);
    }
  }
  __syncthreads();   // all Pass-A reads done -> sxp4 space reusable as smv[2]

  // ---- Pass B + vectorized epilogue, chunked per 2 jy, double-buffered smv.
  // smv[buf] layout (floats): [m/v 0..1 via +2][jyl 0..1][jx 0..13][ch 0..31]
  // buf size 1792 floats = 7168 B; two buffers = 14336 B of 25088.
  float* smv0 = (float*)sxp4;
  const float4* xb = x4 + (size_t)b * NT * (NC / 4) + s * (CSL / 4);
  float4* ob = out4 + (size_t)b * NT * (NC / 4) + s * (CSL / 4);

#pragma unroll 1
  for (int chunk = 0; chunk < 7; ++chunk) {
    float* smv = smv0 + (chunk & 1) * 1792;
    // Pass B for jy = 2*chunk + {0,1} -> current buffer
#pragma unroll
    for (int jyl = 0; jyl < 2; ++jyl) {
      int jy = chunk * 2 + jyl;
      float m = 0.f, q = 0.f;
#pragma unroll
      for (int iy = 0; iy < PSZ; ++iy) {
        float g = sG[jy * PSZ + iy];  // half-wave uniform broadcast
        m += g * t1[iy];
        q += g * t2[iy];
      }
      float p = fmaxf(q - m * m, 0.f);
      smv[(jyl * PSZ + jx) * CSL + ch]       = omw * m;  // mb
      smv[((2 + jyl) * PSZ + jx) * CSL + ch] = ovw * p;  // vb
    }
    __syncthreads();   // buffer (chunk&1) ready; other buffer free for next write

    // epilogue for token rows 4*chunk .. 4*chunk+3 (896 f4-items, 2/thread)
#pragma unroll
    for (int k = 0; k < 2; ++k) {
      int w = tid + BTH * k;          // 0..895
      int slot = w & 7;               // f4 slot within slice
      int r2 = w >> 3;                // 0..111
      int tcol = r2 % 28, trl = r2 / 28;
      int trow = chunk * 4 + trl;
      int t = trow * RESO + tcol;
      int jyl = trl >> 1, jx2 = tcol >> 1;

      float4 mb4 = *(const float4*)&smv[(jyl * PSZ + jx2) * CSL + slot * 4];
      float4 vb4 = *(const float4*)&smv[((2 + jyl) * PSZ + jx2) * CSL + slot * 4];
      float ivv = tstat[t][0];
      float mr = mw * tstat[t][1];
      float vr = vw * tstat[t][2] + EPSV;
      float4 wv = sWB[0][slot], bv = sWB[1][slot];

      float4 xv = xb[(size_t)t * (NC / 4) + slot];
      float4 r;
      r.x = (xv.x * ivv - (mb4.x + mr)) * rsqrtf(vb4.x + vr) * wv.x + bv.x;
      r.y = (xv.y * ivv - (mb4.y + mr)) * rsqrtf(vb4.y + vr) * wv.y + bv.y;
      r.z = (xv.z * ivv - (mb4.z + mr)) * rsqrtf(vb4.z + vr) * wv.z + bv.z;
      r.w = (xv.w * ivv - (mb4.w + mr)) * rsqrtf(vb4.w + vr) * wv.w + bv.w;
      ob[(size_t)t * (NC / 4) + slot] = r;
    }
    // no trailing barrier: next Pass B writes the OTHER buffer
  }
}

// ---------------------------------------------------------------------------
extern "C" void kernel_launch(void* const* d_in, const int* in_sizes, int n_in,
                              void* d_out, int out_size, void* d_ws, size_t ws_size,
                              hipStream_t stream) {
  const float* x     = (const float*)d_in[0];
  const float* wgt   = (const float*)d_in[1];
  const float* bias  = (const float*)d_in[2];
  const float* mnw   = (const float*)d_in[3];
  const float* vnw   = (const float*)d_in[4];
  const float* pos_w = (const float*)d_in[5];
  // pos_b (d_in[6]) cancels in the softmax — unused.
  float* out = (float*)d_out;

  float* ws      = (float*)d_ws;
  float* inv_m2  = ws;                              // NB*NT*NH = 100352
  float* mean_ln = inv_m2 + (size_t)NB * NT * NH;   // 25088
  float* var_ln  = mean_ln + (size_t)NB * NT;       // 25088
  float* xp      = var_ln + (size_t)NB * NT;        // NB*NP*NC = 4816896 (16B aligned)
  // total ~19.9 MB of workspace

  hipLaunchKernelGGL(k_norm_pool, dim3(NB * NP), dim3(256), 0, stream,
                     x, inv_m2, mean_ln, var_ln, (float4*)xp);
  hipLaunchKernelGGL(k_fused, dim3(NB * NSLC), dim3(BTH), 0, stream,
                     (const float4*)xp, pos_w, mnw, vnw, (const float4*)x,
                     (const float4*)wgt, (const float4*)bias,
                     inv_m2, mean_ln, var_ln, (float4*)out);
}